// Round 1
// baseline (548.804 us; speedup 1.0000x reference)
//
#include <hip/hip_runtime.h>
#include <cstdint>

typedef unsigned short ushort_t;
typedef __attribute__((ext_vector_type(8))) __bf16 bf16x8;
typedef __attribute__((ext_vector_type(4))) float f32x4;
typedef __attribute__((ext_vector_type(4))) int i32x4;

#define NG 128
#define NP 32
#define NH 64
#define ND1 512
#define ND2 1024

__device__ inline ushort_t f2bf(float f) {
    uint32_t u = __float_as_uint(f);
    uint32_t r = (u + 0x7FFFu + ((u >> 16) & 1u)) >> 16;
    return (ushort_t)r;
}

// K0: fold layer-1 weights: Mws[2][512] = Ws@W1a, u[512] = Wv@W1c,
//     v[512] = bs@W1a + bv@W1c + b1
__global__ void k0_prep(const float* __restrict__ Ws, const float* __restrict__ bs,
                        const float* __restrict__ Wv, const float* __restrict__ bv,
                        const float* __restrict__ W1, const float* __restrict__ b1,
                        float* __restrict__ Mws, float* __restrict__ uo, float* __restrict__ vo) {
    int ch = threadIdx.x;  // 512
    float m0 = 0.f, m1 = 0.f, uu = 0.f, vv = b1[ch];
    for (int e = 0; e < 64; e++) {
        float w1a = W1[e * ND1 + ch];
        float w1c = W1[(128 + e) * ND1 + ch];
        m0 += Ws[e] * w1a;
        m1 += Ws[64 + e] * w1a;
        uu += Wv[e] * w1c;
        vv += bs[e] * w1a + bv[e] * w1c;
    }
    Mws[ch] = m0; Mws[ND1 + ch] = m1; uo[ch] = uu; vo[ch] = vv;
}

// K0b: W2 [512,1024] fp32 -> W2T [1024][512] bf16 (tiled transpose)
__global__ void k0b_w2t(const float* __restrict__ W2, ushort_t* __restrict__ W2T) {
    __shared__ ushort_t tile[64][65];
    int kb = blockIdx.x & 7, nb = blockIdx.x >> 3;  // 8 k-tiles x 16 n-tiles
    int t = threadIdx.x;
    #pragma unroll
    for (int e = 0; e < 16; e++) {
        int lin = t + e * 256;
        int k = lin >> 6, n = lin & 63;
        tile[k][n] = f2bf(W2[(kb * 64 + k) * ND2 + nb * 64 + n]);
    }
    __syncthreads();
    #pragma unroll
    for (int e = 0; e < 16; e++) {
        int lin = t + e * 256;
        int k = lin & 63, n = lin >> 6;
        W2T[(nb * 64 + n) * ND1 + kb * 64 + k] = tile[k][n];
    }
}

// K2: per (g,ch): compute c_j, q_j, analytic BN1 stats, emit
//     u1[g,j,ch] = (q_j + c_j)*A1 + B1   and   w1[g,i,ch] = q_i*A1
__global__ void k2_group(const float* __restrict__ hstates, const float* __restrict__ pos,
                         const float* __restrict__ spd, const float* __restrict__ W1,
                         const float* __restrict__ g1, const float* __restrict__ be1,
                         const float* __restrict__ Mws, const float* __restrict__ uo,
                         const float* __restrict__ vo,
                         float* __restrict__ u1, float* __restrict__ w1) {
    __shared__ float hid_s[32][64];
    __shared__ float pos_s[32][2];
    __shared__ float spd_s[32];
    int g = blockIdx.x >> 1;
    int ch = ((blockIdx.x & 1) << 8) + threadIdx.x;
    for (int t = threadIdx.x; t < 2048; t += 256) hid_s[t >> 6][t & 63] = hstates[g * 2048 + t];
    if (threadIdx.x < 64) pos_s[threadIdx.x >> 1][threadIdx.x & 1] = pos[g * 64 + threadIdx.x];
    if (threadIdx.x < 32) spd_s[threadIdx.x] = spd[g * 32 + threadIdx.x];
    __syncthreads();
    float m0 = Mws[ch], m1 = Mws[ND1 + ch], uu = uo[ch], vv = vo[ch];
    float cj[32], qj[32];
    #pragma unroll
    for (int j = 0; j < 32; j++) {
        qj[j] = pos_s[j][0] * m0 + pos_s[j][1] * m1;
        cj[j] = vv + spd_s[j] * uu;
    }
    for (int h = 0; h < 64; h++) {
        float w = W1[(64 + h) * ND1 + ch];
        #pragma unroll
        for (int j = 0; j < 32; j++) cj[j] += hid_s[j][h] * w;
    }
    float S1 = 0.f, S2 = 0.f, C1 = 0.f, Cq = 0.f, C2 = 0.f;
    #pragma unroll
    for (int j = 0; j < 32; j++) {
        S1 += qj[j]; S2 += qj[j] * qj[j];
        C1 += cj[j]; Cq += cj[j] * qj[j]; C2 += cj[j] * cj[j];
    }
    float mean = C1 * (1.0f / 32.0f);
    float sumsq = 64.f * S2 - 2.f * S1 * S1 + 64.f * Cq - 2.f * S1 * C1 + 32.f * C2;
    float var = sumsq * (1.0f / 1024.0f) - mean * mean;
    float A1 = rsqrtf(var + 1e-5f) * g1[ch];
    float B1 = be1[ch] - mean * A1;
    #pragma unroll
    for (int j = 0; j < 32; j++) {
        u1[(g * 32 + j) * ND1 + ch] = (qj[j] + cj[j]) * A1 + B1;
        w1[(g * 32 + j) * ND1 + ch] = qj[j] * A1;
    }
}

// K3: per group fused GEMM: h1 = relu(u1[j]-w1[i]) (bf16, on the fly) @ W2T
// Tile: BM=64 edges x BN=128 cols, BK=64, 4 waves (2x2), 16x16x32 MFMA.
// Epilogue: per (i,col) max/min over j (wave-local), per (i,col) sum/sumsq partials.
__global__ __launch_bounds__(256, 2) void k3_gemm(
        const float* __restrict__ u1, const float* __restrict__ w1,
        const ushort_t* __restrict__ W2T, const float* __restrict__ b2,
        float* __restrict__ maxv, float* __restrict__ minv,
        float* __restrict__ psum, float* __restrict__ psq) {
    __shared__ __align__(16) ushort_t a_lds[64 * 64];
    __shared__ __align__(16) ushort_t b_lds[128 * 64];
    int bid = blockIdx.x;
    int g = bid >> 7;
    int t = bid & 127;
    int mt = t & 15, nt = t >> 4;
    int tid = threadIdx.x;
    const float* u1g = u1 + g * 32 * ND1;
    const float* w1g = w1 + g * 32 * ND1;

    int wid = tid >> 6, l = tid & 63;
    int wm = wid >> 1, wn = wid & 1;
    int lo = l & 15, lhi = l >> 4;

    // staging decomposition
    int sr = tid >> 2;          // A row 0..63
    int skq = tid & 3;          // 16-float chunk
    int sj = sr & 31;
    int si = sr >> 5;
    const float* u1row = u1g + sj * ND1;
    const float* w1row = w1g + (mt * 2 + si) * ND1;
    int br = tid >> 1;          // B row (n) 0..127
    int bh = tid & 1;
    const ushort_t* w2row = W2T + (nt * 128 + br) * ND1;

    f32x4 acc[2][4];
    #pragma unroll
    for (int a = 0; a < 2; a++)
        #pragma unroll
        for (int b = 0; b < 4; b++) acc[a][b] = (f32x4){0.f, 0.f, 0.f, 0.f};

    for (int kt = 0; kt < 8; kt++) {
        int k0 = kt * 64;
        // ---- A stage: compute h1 = relu(u1 - w1), bf16, swizzled ds_write
        {
            const float4* pu = reinterpret_cast<const float4*>(u1row + k0 + skq * 16);
            const float4* pw = reinterpret_cast<const float4*>(w1row + k0 + skq * 16);
            uint32_t pk[8];
            #pragma unroll
            for (int q = 0; q < 4; q++) {
                float4 ua = pu[q], wa = pw[q];
                float y0 = fmaxf(ua.x - wa.x, 0.f);
                float y1 = fmaxf(ua.y - wa.y, 0.f);
                float y2 = fmaxf(ua.z - wa.z, 0.f);
                float y3 = fmaxf(ua.w - wa.w, 0.f);
                pk[q * 2 + 0] = (uint32_t)f2bf(y0) | ((uint32_t)f2bf(y1) << 16);
                pk[q * 2 + 1] = (uint32_t)f2bf(y2) | ((uint32_t)f2bf(y3) << 16);
            }
            int c0 = skq * 2, c1 = skq * 2 + 1;
            i32x4 v0 = {(int)pk[0], (int)pk[1], (int)pk[2], (int)pk[3]};
            i32x4 v1 = {(int)pk[4], (int)pk[5], (int)pk[6], (int)pk[7]};
            *reinterpret_cast<i32x4*>(reinterpret_cast<char*>(a_lds) + sr * 128 + ((c0 ^ (sr & 7)) << 4)) = v0;
            *reinterpret_cast<i32x4*>(reinterpret_cast<char*>(a_lds) + sr * 128 + ((c1 ^ (sr & 7)) << 4)) = v1;
        }
        // ---- B stage: W2T bf16, swizzled ds_write
        {
            const i32x4* pb = reinterpret_cast<const i32x4*>(w2row + k0 + bh * 32);
            #pragma unroll
            for (int q = 0; q < 4; q++) {
                i32x4 bv4 = pb[q];
                int c = bh * 4 + q;
                *reinterpret_cast<i32x4*>(reinterpret_cast<char*>(b_lds) + br * 128 + ((c ^ (br & 7)) << 4)) = bv4;
            }
        }
        __syncthreads();
        // ---- fragments + MFMA
        bf16x8 af[2][2];
        #pragma unroll
        for (int fr = 0; fr < 2; fr++)
            #pragma unroll
            for (int kf = 0; kf < 2; kf++) {
                int row = wm * 32 + fr * 16 + lo;
                int c = kf * 4 + lhi;
                af[fr][kf] = *reinterpret_cast<const bf16x8*>(
                    reinterpret_cast<const char*>(a_lds) + row * 128 + ((c ^ (row & 7)) << 4));
            }
        bf16x8 bfr[4][2];
        #pragma unroll
        for (int fc = 0; fc < 4; fc++)
            #pragma unroll
            for (int kf = 0; kf < 2; kf++) {
                int row = wn * 64 + fc * 16 + lo;
                int c = kf * 4 + lhi;
                bfr[fc][kf] = *reinterpret_cast<const bf16x8*>(
                    reinterpret_cast<const char*>(b_lds) + row * 128 + ((c ^ (row & 7)) << 4));
            }
        #pragma unroll
        for (int fr = 0; fr < 2; fr++)
            #pragma unroll
            for (int fc = 0; fc < 4; fc++) {
                acc[fr][fc] = __builtin_amdgcn_mfma_f32_16x16x32_bf16(af[fr][0], bfr[fc][0], acc[fr][fc], 0, 0, 0);
                acc[fr][fc] = __builtin_amdgcn_mfma_f32_16x16x32_bf16(af[fr][1], bfr[fc][1], acc[fr][fc], 0, 0, 0);
            }
        __syncthreads();
    }
    // ---- epilogue: wave (wm,wn) owns i = mt*2+wm fully (32 j-rows) for 64 cols
    int i_glob = g * 32 + mt * 2 + wm;
    #pragma unroll
    for (int fc = 0; fc < 4; fc++) {
        int col = nt * 128 + wn * 64 + fc * 16 + lo;
        float b2v = b2[col];
        float mx = -1e30f, mn = 1e30f, sm = 0.f, sq = 0.f;
        #pragma unroll
        for (int fr = 0; fr < 2; fr++)
            #pragma unroll
            for (int r = 0; r < 4; r++) {
                float y = acc[fr][fc][r] + b2v;
                mx = fmaxf(mx, y); mn = fminf(mn, y);
                sm += y; sq += y * y;
            }
        #pragma unroll
        for (int mask = 16; mask < 64; mask <<= 1) {
            mx = fmaxf(mx, __shfl_xor(mx, mask, 64));
            mn = fminf(mn, __shfl_xor(mn, mask, 64));
            sm += __shfl_xor(sm, mask, 64);
            sq += __shfl_xor(sq, mask, 64);
        }
        if (lhi == 0) {
            int idx = i_glob * ND2 + col;
            maxv[idx] = mx; minv[idx] = mn; psum[idx] = sm; psq[idx] = sq;
        }
    }
}

// K4: finalize BN2 + relu + max-pool select
__global__ void k4_final(const float* __restrict__ maxv, const float* __restrict__ minv,
                         const float* __restrict__ psum, const float* __restrict__ psq,
                         const float* __restrict__ g2, const float* __restrict__ be2,
                         float* __restrict__ out) {
    int g = blockIdx.x >> 2;
    int col = ((blockIdx.x & 3) << 8) + threadIdx.x;
    float s = 0.f, q = 0.f;
    for (int i = 0; i < 32; i++) {
        int idx = (g * 32 + i) * ND2 + col;
        s += psum[idx]; q += psq[idx];
    }
    float m2 = s * (1.f / 1024.f);
    float var = q * (1.f / 1024.f) - m2 * m2;
    float A2 = rsqrtf(var + 1e-5f) * g2[col];
    float B2 = be2[col] - m2 * A2;
    for (int i = 0; i < 32; i++) {
        int idx = (g * 32 + i) * ND2 + col;
        float y = (A2 >= 0.f) ? maxv[idx] : minv[idx];
        out[idx] = fmaxf(y * A2 + B2, 0.f);
    }
}

extern "C" void kernel_launch(void* const* d_in, const int* in_sizes, int n_in,
                              void* d_out, int out_size, void* d_ws, size_t ws_size,
                              hipStream_t stream) {
    (void)in_sizes; (void)n_in; (void)out_size; (void)ws_size;
    const float* h_states = (const float*)d_in[0];
    // d_in[1] seq_start_end unused (uniform groups)
    const float* end_pos  = (const float*)d_in[2];
    const float* end_spd  = (const float*)d_in[3];
    const float* Ws  = (const float*)d_in[4];
    const float* bs  = (const float*)d_in[5];
    const float* Wv  = (const float*)d_in[6];
    const float* bv  = (const float*)d_in[7];
    const float* W1  = (const float*)d_in[8];
    const float* b1  = (const float*)d_in[9];
    const float* g1  = (const float*)d_in[10];
    const float* be1 = (const float*)d_in[11];
    const float* W2  = (const float*)d_in[12];
    const float* b2  = (const float*)d_in[13];
    const float* g2  = (const float*)d_in[14];
    const float* be2 = (const float*)d_in[15];
    float* ws = (float*)d_ws;
    float* Mws  = ws + 0;         // 1024
    float* uo   = ws + 1024;      // 512
    float* vo   = ws + 1536;      // 512
    float* u1   = ws + 2048;      // 2097152
    float* w1x  = ws + 2099200;   // 2097152
    ushort_t* W2T = (ushort_t*)(ws + 4196352);  // 524288 bf16
    float* maxv = ws + 4458496;   // 4194304
    float* minv = ws + 8652800;   // 4194304
    float* psum = ws + 12847104;  // 4194304
    float* psq  = ws + 17041408;  // 4194304  (total ~85 MB)
    float* out = (float*)d_out;

    hipLaunchKernelGGL(k0_prep, dim3(1), dim3(512), 0, stream, Ws, bs, Wv, bv, W1, b1, Mws, uo, vo);
    hipLaunchKernelGGL(k0b_w2t, dim3(128), dim3(256), 0, stream, W2, W2T);
    hipLaunchKernelGGL(k2_group, dim3(256), dim3(256), 0, stream,
                       h_states, end_pos, end_spd, W1, g1, be1, Mws, uo, vo, u1, w1x);
    hipLaunchKernelGGL(k3_gemm, dim3(16384), dim3(256), 0, stream,
                       u1, w1x, W2T, b2, maxv, minv, psum, psq);
    hipLaunchKernelGGL(k4_final, dim3(512), dim3(256), 0, stream,
                       maxv, minv, psum, psq, g2, be2, out);
}

// Round 4
// 338.151 us; speedup vs baseline: 1.6230x; 1.6230x over previous
//
#include <hip/hip_runtime.h>
#include <cstdint>

typedef unsigned short ushort_t;
typedef __attribute__((ext_vector_type(8))) __bf16 bf16x8;
typedef __attribute__((ext_vector_type(4))) float f32x4;
typedef __attribute__((ext_vector_type(4))) int i32x4;

#define NG 128
#define NP 32
#define NH 64
#define ND1 512
#define ND2 1024

__device__ inline ushort_t f2bf(float f) {
    uint32_t u = __float_as_uint(f);
    uint32_t r = (u + 0x7FFFu + ((u >> 16) & 1u)) >> 16;
    return (ushort_t)r;
}

#define GLL16(gp, lp) __builtin_amdgcn_global_load_lds( \
    (const __attribute__((address_space(1))) unsigned int*)(gp), \
    (__attribute__((address_space(3))) unsigned int*)(lp), 16, 0, 0)

// K0: fold layer-1 weights: Mws[2][512] = Ws@W1a, u[512] = Wv@W1c,
//     v[512] = bs@W1a + bv@W1c + b1
__global__ void k0_prep(const float* __restrict__ Ws, const float* __restrict__ bs,
                        const float* __restrict__ Wv, const float* __restrict__ bv,
                        const float* __restrict__ W1, const float* __restrict__ b1,
                        float* __restrict__ Mws, float* __restrict__ uo, float* __restrict__ vo) {
    int ch = threadIdx.x;  // 512
    float m0 = 0.f, m1 = 0.f, uu = 0.f, vv = b1[ch];
    for (int e = 0; e < 64; e++) {
        float w1a = W1[e * ND1 + ch];
        float w1c = W1[(128 + e) * ND1 + ch];
        m0 += Ws[e] * w1a;
        m1 += Ws[64 + e] * w1a;
        uu += Wv[e] * w1c;
        vv += bs[e] * w1a + bv[e] * w1c;
    }
    Mws[ch] = m0; Mws[ND1 + ch] = m1; uo[ch] = uu; vo[ch] = vv;
}

// K0b: W2 [512,1024] fp32 -> W2T [1024][512] bf16 (tiled transpose)
__global__ void k0b_w2t(const float* __restrict__ W2, ushort_t* __restrict__ W2T) {
    __shared__ ushort_t tile[64][65];
    int kb = blockIdx.x & 7, nb = blockIdx.x >> 3;  // 8 k-tiles x 16 n-tiles
    int t = threadIdx.x;
    #pragma unroll
    for (int e = 0; e < 16; e++) {
        int lin = t + e * 256;
        int k = lin >> 6, n = lin & 63;
        tile[k][n] = f2bf(W2[(kb * 64 + k) * ND2 + nb * 64 + n]);
    }
    __syncthreads();
    #pragma unroll
    for (int e = 0; e < 16; e++) {
        int lin = t + e * 256;
        int k = lin & 63, n = lin >> 6;
        W2T[(nb * 64 + n) * ND1 + kb * 64 + k] = tile[k][n];
    }
}

// K2: per (g,ch): compute c_j, q_j, analytic BN1 stats, emit
//     u1[g,j,ch] = (q_j + c_j)*A1 + B1   and   w1[g,i,ch] = q_i*A1
__global__ void k2_group(const float* __restrict__ hstates, const float* __restrict__ pos,
                         const float* __restrict__ spd, const float* __restrict__ W1,
                         const float* __restrict__ g1, const float* __restrict__ be1,
                         const float* __restrict__ Mws, const float* __restrict__ uo,
                         const float* __restrict__ vo,
                         float* __restrict__ u1, float* __restrict__ w1) {
    __shared__ float hid_s[32][64];
    __shared__ float pos_s[32][2];
    __shared__ float spd_s[32];
    int g = blockIdx.x >> 1;
    int ch = ((blockIdx.x & 1) << 8) + threadIdx.x;
    for (int t = threadIdx.x; t < 2048; t += 256) hid_s[t >> 6][t & 63] = hstates[g * 2048 + t];
    if (threadIdx.x < 64) pos_s[threadIdx.x >> 1][threadIdx.x & 1] = pos[g * 64 + threadIdx.x];
    if (threadIdx.x < 32) spd_s[threadIdx.x] = spd[g * 32 + threadIdx.x];
    __syncthreads();
    float m0 = Mws[ch], m1 = Mws[ND1 + ch], uu = uo[ch], vv = vo[ch];
    float cj[32], qj[32];
    #pragma unroll
    for (int j = 0; j < 32; j++) {
        qj[j] = pos_s[j][0] * m0 + pos_s[j][1] * m1;
        cj[j] = vv + spd_s[j] * uu;
    }
    for (int h = 0; h < 64; h++) {
        float w = W1[(64 + h) * ND1 + ch];
        #pragma unroll
        for (int j = 0; j < 32; j++) cj[j] += hid_s[j][h] * w;
    }
    float S1 = 0.f, S2 = 0.f, C1 = 0.f, Cq = 0.f, C2 = 0.f;
    #pragma unroll
    for (int j = 0; j < 32; j++) {
        S1 += qj[j]; S2 += qj[j] * qj[j];
        C1 += cj[j]; Cq += cj[j] * qj[j]; C2 += cj[j] * cj[j];
    }
    float mean = C1 * (1.0f / 32.0f);
    float sumsq = 64.f * S2 - 2.f * S1 * S1 + 64.f * Cq - 2.f * S1 * C1 + 32.f * C2;
    float var = sumsq * (1.0f / 1024.0f) - mean * mean;
    float A1 = rsqrtf(var + 1e-5f) * g1[ch];
    float B1 = be1[ch] - mean * A1;
    #pragma unroll
    for (int j = 0; j < 32; j++) {
        u1[(g * 32 + j) * ND1 + ch] = (qj[j] + cj[j]) * A1 + B1;
        w1[(g * 32 + j) * ND1 + ch] = qj[j] * A1;
    }
}

// K2b: materialize h1[row][k] = relu(u1[g,j,k] - w1[g,i,k]) as bf16.
// row = gc*1024 + i*32 + j (within chunk). Each thread: 8 bf16 (16B store).
__global__ void k2b_h1(const float* __restrict__ u1c, const float* __restrict__ w1c,
                       ushort_t* __restrict__ h1) {
    int t = blockIdx.x * 256 + threadIdx.x;
    int k8 = t & 63;          // which 8-wide k chunk (512/8)
    int row = t >> 6;
    int gc = row >> 10, rem = row & 1023;
    int i = rem >> 5, j = rem & 31;
    const float4* pu = reinterpret_cast<const float4*>(u1c + (size_t)(gc * 32 + j) * ND1 + k8 * 8);
    const float4* pw = reinterpret_cast<const float4*>(w1c + (size_t)(gc * 32 + i) * ND1 + k8 * 8);
    float4 ua = pu[0], ub = pu[1], wa = pw[0], wb = pw[1];
    uint32_t p0 = (uint32_t)f2bf(fmaxf(ua.x - wa.x, 0.f)) | ((uint32_t)f2bf(fmaxf(ua.y - wa.y, 0.f)) << 16);
    uint32_t p1 = (uint32_t)f2bf(fmaxf(ua.z - wa.z, 0.f)) | ((uint32_t)f2bf(fmaxf(ua.w - wa.w, 0.f)) << 16);
    uint32_t p2 = (uint32_t)f2bf(fmaxf(ub.x - wb.x, 0.f)) | ((uint32_t)f2bf(fmaxf(ub.y - wb.y, 0.f)) << 16);
    uint32_t p3 = (uint32_t)f2bf(fmaxf(ub.z - wb.z, 0.f)) | ((uint32_t)f2bf(fmaxf(ub.w - wb.w, 0.f)) << 16);
    i32x4 v = {(int)p0, (int)p1, (int)p2, (int)p3};
    *reinterpret_cast<i32x4*>(h1 + (size_t)row * ND1 + k8 * 8) = v;
}

__global__ void kz_zero(float* __restrict__ p, int n) {
    int t = blockIdx.x * 256 + threadIdx.x;
    if (t < n) p[t] = 0.f;
}

// K3: m97-structure GEMM. A = h1 chunk [CG*1024][512] bf16, B = W2T [1024][512] bf16.
// 128x128 tile, BK=32, 4 waves (2x2), per-wave 64x64, global_load_lds(16) staging,
// linear LDS, 2 barriers/K-step. Epilogue: per-(i,col) max/min over j + fp32 atomics
// for per-(g,col) sum/sumsq (raw GEMM values; b2 folded in k4).
__global__ __launch_bounds__(256, 2) void k3_gemm(
        const ushort_t* __restrict__ h1, const ushort_t* __restrict__ W2T,
        float* __restrict__ maxv, float* __restrict__ minv,
        float* __restrict__ psum, float* __restrict__ psq, int g0) {
    __shared__ __align__(16) ushort_t a_lds[128 * 32];
    __shared__ __align__(16) ushort_t b_lds[128 * 32];
    int b = blockIdx.x;
    // XCD co-location: b&7 = mt%8 -> all 8 nt-blocks of an mt land on one XCD (round-robin heuristic)
    int mt = (b & 7) + ((b >> 6) << 3);
    int nt = (b >> 3) & 7;
    int tid = threadIdx.x;
    int w = tid >> 6, l = tid & 63;
    int wm = w >> 1, wn = w & 1;
    int lo = l & 15, lhi = l >> 4;

    const char* Ag = reinterpret_cast<const char*>(h1) + (size_t)mt * 128 * ND1 * 2;
    const char* Bg = reinterpret_cast<const char*>(W2T) + (size_t)nt * 128 * ND1 * 2;
    // staging: per wave 2 chunks of 1KB (16 rows each); lane l -> row (l>>2), bytes (l&3)*16
    int soff0 = (w * 32 + (l >> 2)) * 1024 + (l & 3) * 16;        // chunk q=0
    int soff1 = soff0 + 16 * 1024;                                // chunk q=1
    char* alds0 = reinterpret_cast<char*>(a_lds) + (w * 2 + 0) * 1024;
    char* alds1 = reinterpret_cast<char*>(a_lds) + (w * 2 + 1) * 1024;
    char* blds0 = reinterpret_cast<char*>(b_lds) + (w * 2 + 0) * 1024;
    char* blds1 = reinterpret_cast<char*>(b_lds) + (w * 2 + 1) * 1024;

    f32x4 acc[4][4];
    #pragma unroll
    for (int a = 0; a < 4; a++)
        #pragma unroll
        for (int c = 0; c < 4; c++) acc[a][c] = (f32x4){0.f, 0.f, 0.f, 0.f};

    int aoff = (wm * 64 + lo) * 64 + lhi * 16;   // ds_read base for A frags (bytes)
    int boff = (wn * 64 + lo) * 64 + lhi * 16;

    for (int kt = 0; kt < 16; kt++) {
        int kb = kt * 64;  // byte offset of K-tile within a 1024B row
        GLL16(Ag + soff0 + kb, alds0);
        GLL16(Ag + soff1 + kb, alds1);
        GLL16(Bg + soff0 + kb, blds0);
        GLL16(Bg + soff1 + kb, blds1);
        __syncthreads();
        bf16x8 af[4], bfv[4];
        #pragma unroll
        for (int fr = 0; fr < 4; fr++)
            af[fr] = *reinterpret_cast<const bf16x8*>(reinterpret_cast<const char*>(a_lds) + aoff + fr * 1024);
        #pragma unroll
        for (int fc = 0; fc < 4; fc++)
            bfv[fc] = *reinterpret_cast<const bf16x8*>(reinterpret_cast<const char*>(b_lds) + boff + fc * 1024);
        #pragma unroll
        for (int fr = 0; fr < 4; fr++)
            #pragma unroll
            for (int fc = 0; fc < 4; fc++)
                acc[fr][fc] = __builtin_amdgcn_mfma_f32_16x16x32_bf16(af[fr], bfv[fc], acc[fr][fc], 0, 0, 0);
        __syncthreads();
    }

    // epilogue: wave rows = wm*64 + (fr*16 + lhi*4 + r); i spans 2 values
    int g = g0 + (mt >> 3);
    int ib = ((mt & 7) << 2) + wm * 2;
    #pragma unroll
    for (int fc = 0; fc < 4; fc++) {
        int col = nt * 128 + wn * 64 + fc * 16 + lo;
        float mx0 = -1e30f, mn0 = 1e30f, mx1 = -1e30f, mn1 = 1e30f, sm = 0.f, sq = 0.f;
        #pragma unroll
        for (int fr = 0; fr < 2; fr++)
            #pragma unroll
            for (int r = 0; r < 4; r++) {
                float y = acc[fr][fc][r];
                mx0 = fmaxf(mx0, y); mn0 = fminf(mn0, y);
                sm += y; sq += y * y;
            }
        #pragma unroll
        for (int fr = 2; fr < 4; fr++)
            #pragma unroll
            for (int r = 0; r < 4; r++) {
                float y = acc[fr][fc][r];
                mx1 = fmaxf(mx1, y); mn1 = fminf(mn1, y);
                sm += y; sq += y * y;
            }
        #pragma unroll
        for (int mask = 16; mask < 64; mask <<= 1) {
            mx0 = fmaxf(mx0, __shfl_xor(mx0, mask, 64));
            mn0 = fminf(mn0, __shfl_xor(mn0, mask, 64));
            mx1 = fmaxf(mx1, __shfl_xor(mx1, mask, 64));
            mn1 = fminf(mn1, __shfl_xor(mn1, mask, 64));
            sm += __shfl_xor(sm, mask, 64);
            sq += __shfl_xor(sq, mask, 64);
        }
        if (lhi == 0) {
            size_t i0 = (size_t)(g * 32 + ib) * ND2 + col;
            maxv[i0] = mx0; minv[i0] = mn0;
            maxv[i0 + ND2] = mx1; minv[i0 + ND2] = mn1;
            atomicAdd(&psum[g * ND2 + col], sm);
            atomicAdd(&psq[g * ND2 + col], sq);
        }
    }
}

// K4: finalize BN2 (+b2 folded analytically) + relu + max-pool select
__global__ void k4_final(const float* __restrict__ maxv, const float* __restrict__ minv,
                         const float* __restrict__ psum, const float* __restrict__ psq,
                         const float* __restrict__ b2, const float* __restrict__ g2,
                         const float* __restrict__ be2, float* __restrict__ out) {
    int g = blockIdx.x >> 2;
    int col = ((blockIdx.x & 3) << 8) + threadIdx.x;
    float b2v = b2[col];
    float s = psum[g * ND2 + col] * (1.f / 1024.f);   // E[z]
    float q = psq[g * ND2 + col] * (1.f / 1024.f);    // E[z^2]
    float mean = s + b2v;
    float var = q + 2.f * b2v * s + b2v * b2v - mean * mean;
    float A2 = rsqrtf(var + 1e-5f) * g2[col];
    float B2 = be2[col] - mean * A2;
    for (int i = 0; i < 32; i++) {
        size_t idx = (size_t)(g * 32 + i) * ND2 + col;
        float y = ((A2 >= 0.f) ? maxv[idx] : minv[idx]) + b2v;
        out[idx] = fmaxf(y * A2 + B2, 0.f);
    }
}

extern "C" void kernel_launch(void* const* d_in, const int* in_sizes, int n_in,
                              void* d_out, int out_size, void* d_ws, size_t ws_size,
                              hipStream_t stream) {
    (void)in_sizes; (void)n_in; (void)out_size;
    const float* h_states = (const float*)d_in[0];
    const float* end_pos  = (const float*)d_in[2];
    const float* end_spd  = (const float*)d_in[3];
    const float* Ws  = (const float*)d_in[4];
    const float* bs  = (const float*)d_in[5];
    const float* Wv  = (const float*)d_in[6];
    const float* bv  = (const float*)d_in[7];
    const float* W1  = (const float*)d_in[8];
    const float* b1  = (const float*)d_in[9];
    const float* g1  = (const float*)d_in[10];
    const float* be1 = (const float*)d_in[11];
    const float* W2  = (const float*)d_in[12];
    const float* b2  = (const float*)d_in[13];
    const float* g2  = (const float*)d_in[14];
    const float* be2 = (const float*)d_in[15];
    float* ws = (float*)d_ws;
    float* Mws  = ws + 0;                         // 1024
    float* uo   = ws + 1024;                      // 512
    float* vo   = ws + 1536;                      // 512
    float* u1   = ws + 2048;                      // 2,097,152
    float* w1x  = ws + 2099200;                   // 2,097,152
    ushort_t* W2T = (ushort_t*)(ws + 4196352);    // 524,288 bf16 (262,144 f)
    float* maxv = ws + 4458496;                   // 4,194,304
    float* minv = ws + 8652800;                   // 4,194,304
    float* psum = ws + 12847104;                  // 131,072
    float* psq  = ws + 12978176;                  // 131,072
    ushort_t* h1 = (ushort_t*)(ws + 13109248);    // CG*1024*512 bf16
    float* out = (float*)d_out;

    // pick largest group-chunk CG whose h1 fits the workspace
    const size_t fixed_f = 13109248ULL;
    int CG = 128;
    while (CG > 4 && (fixed_f + (size_t)CG * 262144ULL) * 4ULL > ws_size) CG >>= 1;
    int nch = 128 / CG;

    hipLaunchKernelGGL(k0_prep, dim3(1), dim3(512), 0, stream, Ws, bs, Wv, bv, W1, b1, Mws, uo, vo);
    hipLaunchKernelGGL(k0b_w2t, dim3(128), dim3(256), 0, stream, W2, W2T);
    hipLaunchKernelGGL(k2_group, dim3(256), dim3(256), 0, stream,
                       h_states, end_pos, end_spd, W1, g1, be1, Mws, uo, vo, u1, w1x);
    hipLaunchKernelGGL(kz_zero, dim3(1024), dim3(256), 0, stream, psum, 262144);
    for (int c = 0; c < nch; c++) {
        const float* u1c = u1 + (size_t)c * CG * 32 * ND1;
        const float* w1c = w1x + (size_t)c * CG * 32 * ND1;
        hipLaunchKernelGGL(k2b_h1, dim3(CG * 256), dim3(256), 0, stream, u1c, w1c, h1);
        hipLaunchKernelGGL(k3_gemm, dim3(CG * 64), dim3(256), 0, stream,
                           h1, W2T, maxv, minv, psum, psq, c * CG);
    }
    hipLaunchKernelGGL(k4_final, dim3(512), dim3(256), 0, stream,
                       maxv, minv, psum, psq, b2, g2, be2, out);
}

// Round 5
// 325.052 us; speedup vs baseline: 1.6884x; 1.0403x over previous
//
#include <hip/hip_runtime.h>
#include <cstdint>

typedef unsigned short ushort_t;
typedef __attribute__((ext_vector_type(8))) __bf16 bf16x8;
typedef __attribute__((ext_vector_type(4))) float f32x4;
typedef __attribute__((ext_vector_type(4))) int i32x4;

#define NG 128
#define NP 32
#define NH 64
#define ND1 512
#define ND2 1024

__device__ inline ushort_t f2bf(float f) {
    uint32_t u = __float_as_uint(f);
    uint32_t r = (u + 0x7FFFu + ((u >> 16) & 1u)) >> 16;
    return (ushort_t)r;
}

#define GLL16(gp, lp) __builtin_amdgcn_global_load_lds( \
    (const __attribute__((address_space(1))) unsigned int*)(gp), \
    (__attribute__((address_space(3))) unsigned int*)(lp), 16, 0, 0)

// K2_all: grid 384.
//  blocks 0..255: zero psum/psq + inline weight-fold + per-(g,ch) BN1 analytics,
//                 emit u1 = (q_j+c_j)*A1+B1 and w1 = q_i*A1  (fp32)
//  blocks 256..383: W2 [512,1024] fp32 -> W2T bf16 [1024][512], stored with
//                 chunk swizzle: 16B chunk c of each 128B window at c^(n&7).
__global__ void k2_all(const float* __restrict__ hstates, const float* __restrict__ pos,
                       const float* __restrict__ spd, const float* __restrict__ W1,
                       const float* __restrict__ g1, const float* __restrict__ be1,
                       const float* __restrict__ Ws, const float* __restrict__ bs,
                       const float* __restrict__ Wv, const float* __restrict__ bv,
                       const float* __restrict__ b1, const float* __restrict__ W2,
                       ushort_t* __restrict__ W2T,
                       float* __restrict__ u1, float* __restrict__ w1,
                       float* __restrict__ psum) {
    __shared__ float hid_s[32][64];
    __shared__ float pos_s[32][2];
    __shared__ float spd_s[32];
    __shared__ ushort_t tile[64][65];
    int b = blockIdx.x, tid = threadIdx.x;
    if (b < 256) {
        // zero psum+psq (contiguous 262144 floats)
        int t0 = b * 256 + tid;
        #pragma unroll
        for (int z = 0; z < 4; z++) psum[t0 + z * 65536] = 0.f;
        int g = b >> 1;
        int ch = ((b & 1) << 8) + tid;
        for (int t = tid; t < 2048; t += 256) hid_s[t >> 6][t & 63] = hstates[g * 2048 + t];
        if (tid < 64) pos_s[tid >> 1][tid & 1] = pos[g * 64 + tid];
        if (tid < 32) spd_s[tid] = spd[g * 32 + tid];
        // inline weight fold (was k0_prep): W1 is L2-resident, redundancy is cheap
        float m0 = 0.f, m1 = 0.f, uu = 0.f, vv = b1[ch];
        for (int e = 0; e < 64; e++) {
            float w1a = W1[e * ND1 + ch];
            float w1c = W1[(128 + e) * ND1 + ch];
            m0 += Ws[e] * w1a;
            m1 += Ws[64 + e] * w1a;
            uu += Wv[e] * w1c;
            vv += bs[e] * w1a + bv[e] * w1c;
        }
        __syncthreads();
        float cj[32], qj[32];
        #pragma unroll
        for (int j = 0; j < 32; j++) {
            qj[j] = pos_s[j][0] * m0 + pos_s[j][1] * m1;
            cj[j] = vv + spd_s[j] * uu;
        }
        for (int h = 0; h < 64; h++) {
            float w = W1[(64 + h) * ND1 + ch];
            #pragma unroll
            for (int j = 0; j < 32; j++) cj[j] += hid_s[j][h] * w;
        }
        float S1 = 0.f, S2 = 0.f, C1 = 0.f, Cq = 0.f, C2 = 0.f;
        #pragma unroll
        for (int j = 0; j < 32; j++) {
            S1 += qj[j]; S2 += qj[j] * qj[j];
            C1 += cj[j]; Cq += cj[j] * qj[j]; C2 += cj[j] * cj[j];
        }
        float mean = C1 * (1.0f / 32.0f);
        float sumsq = 64.f * S2 - 2.f * S1 * S1 + 64.f * Cq - 2.f * S1 * C1 + 32.f * C2;
        float var = sumsq * (1.0f / 1024.0f) - mean * mean;
        float A1 = rsqrtf(var + 1e-5f) * g1[ch];
        float B1 = be1[ch] - mean * A1;
        #pragma unroll
        for (int j = 0; j < 32; j++) {
            u1[(g * 32 + j) * ND1 + ch] = (qj[j] + cj[j]) * A1 + B1;
            w1[(g * 32 + j) * ND1 + ch] = qj[j] * A1;
        }
    } else {
        // W2T transpose with swizzled chunk layout
        int tb = b - 256;
        int kb2 = tb & 7, nb = tb >> 3;  // 8 k-tiles x 16 n-tiles
        #pragma unroll
        for (int e = 0; e < 16; e++) {
            int lin = tid + e * 256;
            int k = lin >> 6, n = lin & 63;
            tile[k][n] = f2bf(W2[(kb2 * 64 + k) * ND2 + nb * 64 + n]);
        }
        __syncthreads();
        #pragma unroll
        for (int e = 0; e < 16; e++) {
            int lin = tid + e * 256;
            int kl = lin & 63, nl = lin >> 6;
            int n = nb * 64 + nl, k = kb2 * 64 + kl;
            // ushort index: n*512 + window*64 + swizzled-chunk*8 + (k&7)
            int idx = n * ND1 + ((k >> 6) << 6) + (((((k >> 3) & 7) ^ (n & 7))) << 3) + (k & 7);
            W2T[idx] = tile[kl][nl];
        }
    }
}

// K2b: materialize h1[row][k] = relu(u1[g,j,k] - w1[g,i,k]) as bf16,
// stored with the same chunk swizzle (16B chunk c of each 128B window at c^(row&7)).
__global__ void k2b_h1(const float* __restrict__ u1c, const float* __restrict__ w1c,
                       ushort_t* __restrict__ h1) {
    int t = blockIdx.x * 256 + threadIdx.x;
    int k8 = t & 63;          // which 8-wide k chunk (512/8)
    int row = t >> 6;
    int gc = row >> 10, rem = row & 1023;
    int i = rem >> 5, j = rem & 31;
    const float4* pu = reinterpret_cast<const float4*>(u1c + (size_t)(gc * 32 + j) * ND1 + k8 * 8);
    const float4* pw = reinterpret_cast<const float4*>(w1c + (size_t)(gc * 32 + i) * ND1 + k8 * 8);
    float4 ua = pu[0], ub = pu[1], wa = pw[0], wb = pw[1];
    uint32_t p0 = (uint32_t)f2bf(fmaxf(ua.x - wa.x, 0.f)) | ((uint32_t)f2bf(fmaxf(ua.y - wa.y, 0.f)) << 16);
    uint32_t p1 = (uint32_t)f2bf(fmaxf(ua.z - wa.z, 0.f)) | ((uint32_t)f2bf(fmaxf(ua.w - wa.w, 0.f)) << 16);
    uint32_t p2 = (uint32_t)f2bf(fmaxf(ub.x - wb.x, 0.f)) | ((uint32_t)f2bf(fmaxf(ub.y - wb.y, 0.f)) << 16);
    uint32_t p3 = (uint32_t)f2bf(fmaxf(ub.z - wb.z, 0.f)) | ((uint32_t)f2bf(fmaxf(ub.w - wb.w, 0.f)) << 16);
    i32x4 v = {(int)p0, (int)p1, (int)p2, (int)p3};
    int kt = k8 >> 3, c = k8 & 7;
    *reinterpret_cast<i32x4*>(h1 + (size_t)row * ND1 + (kt << 6) + (((c ^ (row & 7))) << 3)) = v;
}

// K3: 2-phase GEMM, 128x128 tile, BK=64 (8 K-steps, 32 MFMA/wave/step),
// global_load_lds(16) staging into linear LDS; producers pre-swizzled so
// ds_reads use chunk^(row&7) addressing (~4-way max alias).
// Epilogue: per-(i,col) max/min over j + fp32 atomics for per-(g,col) sums.
__global__ __launch_bounds__(256, 2) void k3_gemm(
        const ushort_t* __restrict__ h1, const ushort_t* __restrict__ W2T,
        float* __restrict__ maxv, float* __restrict__ minv,
        float* __restrict__ psum, float* __restrict__ psq, int g0) {
    __shared__ __align__(16) ushort_t a_lds[128 * 64];
    __shared__ __align__(16) ushort_t b_lds[128 * 64];
    int b = blockIdx.x;
    int mt = (b & 7) + ((b >> 6) << 3);
    int nt = (b >> 3) & 7;
    int tid = threadIdx.x;
    int w = tid >> 6, l = tid & 63;
    int wm = w >> 1, wn = w & 1;
    int lo = l & 15, lhi = l >> 4;

    const char* Ag = reinterpret_cast<const char*>(h1) + (size_t)mt * 128 * ND1 * 2;
    const char* Bg = reinterpret_cast<const char*>(W2T) + (size_t)nt * 128 * ND1 * 2;
    // staging: per wave 4 chunks of 1KB (8 rows x 128B each)
    int gbase = (w * 32 + (l >> 3)) * 1024 + (l & 7) * 16;
    char* aldsb = reinterpret_cast<char*>(a_lds) + w * 4096;
    char* bldsb = reinterpret_cast<char*>(b_lds) + w * 4096;

    f32x4 acc[4][4];
    #pragma unroll
    for (int a = 0; a < 4; a++)
        #pragma unroll
        for (int c = 0; c < 4; c++) acc[a][c] = (f32x4){0.f, 0.f, 0.f, 0.f};

    for (int kt = 0; kt < 8; kt++) {
        int kb = kt * 128;  // byte offset of K-window within a 1024B row
        #pragma unroll
        for (int q = 0; q < 4; q++) {
            GLL16(Ag + gbase + q * 8192 + kb, aldsb + q * 1024);
            GLL16(Bg + gbase + q * 8192 + kb, bldsb + q * 1024);
        }
        __syncthreads();
        bf16x8 af[4][2], bfv[4][2];
        #pragma unroll
        for (int fr = 0; fr < 4; fr++) {
            int r = wm * 64 + fr * 16 + lo;
            #pragma unroll
            for (int kc = 0; kc < 2; kc++)
                af[fr][kc] = *reinterpret_cast<const bf16x8*>(
                    reinterpret_cast<const char*>(a_lds) + r * 128 + (((kc * 4 + lhi) ^ (r & 7)) << 4));
        }
        #pragma unroll
        for (int fc = 0; fc < 4; fc++) {
            int r = wn * 64 + fc * 16 + lo;
            #pragma unroll
            for (int kc = 0; kc < 2; kc++)
                bfv[fc][kc] = *reinterpret_cast<const bf16x8*>(
                    reinterpret_cast<const char*>(b_lds) + r * 128 + (((kc * 4 + lhi) ^ (r & 7)) << 4));
        }
        #pragma unroll
        for (int kc = 0; kc < 2; kc++)
            #pragma unroll
            for (int fr = 0; fr < 4; fr++)
                #pragma unroll
                for (int fc = 0; fc < 4; fc++)
                    acc[fr][fc] = __builtin_amdgcn_mfma_f32_16x16x32_bf16(af[fr][kc], bfv[fc][kc], acc[fr][fc], 0, 0, 0);
        __syncthreads();
    }

    // epilogue: wave rows = wm*64 + (fr*16 + lhi*4 + r); i spans 2 values
    int g = g0 + (mt >> 3);
    int ib = ((mt & 7) << 2) + wm * 2;
    #pragma unroll
    for (int fc = 0; fc < 4; fc++) {
        int col = nt * 128 + wn * 64 + fc * 16 + lo;
        float mx0 = -1e30f, mn0 = 1e30f, mx1 = -1e30f, mn1 = 1e30f, sm = 0.f, sq = 0.f;
        #pragma unroll
        for (int fr = 0; fr < 2; fr++)
            #pragma unroll
            for (int r = 0; r < 4; r++) {
                float y = acc[fr][fc][r];
                mx0 = fmaxf(mx0, y); mn0 = fminf(mn0, y);
                sm += y; sq += y * y;
            }
        #pragma unroll
        for (int fr = 2; fr < 4; fr++)
            #pragma unroll
            for (int r = 0; r < 4; r++) {
                float y = acc[fr][fc][r];
                mx1 = fmaxf(mx1, y); mn1 = fminf(mn1, y);
                sm += y; sq += y * y;
            }
        #pragma unroll
        for (int mask = 16; mask < 64; mask <<= 1) {
            mx0 = fmaxf(mx0, __shfl_xor(mx0, mask, 64));
            mn0 = fminf(mn0, __shfl_xor(mn0, mask, 64));
            mx1 = fmaxf(mx1, __shfl_xor(mx1, mask, 64));
            mn1 = fminf(mn1, __shfl_xor(mn1, mask, 64));
            sm += __shfl_xor(sm, mask, 64);
            sq += __shfl_xor(sq, mask, 64);
        }
        if (lhi == 0) {
            size_t i0 = (size_t)(g * 32 + ib) * ND2 + col;
            maxv[i0] = mx0; minv[i0] = mn0;
            maxv[i0 + ND2] = mx1; minv[i0 + ND2] = mn1;
            atomicAdd(&psum[g * ND2 + col], sm);
            atomicAdd(&psq[g * ND2 + col], sq);
        }
    }
}

// K4: finalize BN2 (+b2 folded analytically) + relu + max-pool select
__global__ void k4_final(const float* __restrict__ maxv, const float* __restrict__ minv,
                         const float* __restrict__ psum, const float* __restrict__ psq,
                         const float* __restrict__ b2, const float* __restrict__ g2,
                         const float* __restrict__ be2, float* __restrict__ out) {
    int g = blockIdx.x >> 2;
    int col = ((blockIdx.x & 3) << 8) + threadIdx.x;
    float b2v = b2[col];
    float s = psum[g * ND2 + col] * (1.f / 1024.f);   // E[z]
    float q = psq[g * ND2 + col] * (1.f / 1024.f);    // E[z^2]
    float mean = s + b2v;
    float var = q + 2.f * b2v * s + b2v * b2v - mean * mean;
    float A2 = rsqrtf(var + 1e-5f) * g2[col];
    float B2 = be2[col] - mean * A2;
    for (int i = 0; i < 32; i++) {
        size_t idx = (size_t)(g * 32 + i) * ND2 + col;
        float y = ((A2 >= 0.f) ? maxv[idx] : minv[idx]) + b2v;
        out[idx] = fmaxf(y * A2 + B2, 0.f);
    }
}

extern "C" void kernel_launch(void* const* d_in, const int* in_sizes, int n_in,
                              void* d_out, int out_size, void* d_ws, size_t ws_size,
                              hipStream_t stream) {
    (void)in_sizes; (void)n_in; (void)out_size;
    const float* h_states = (const float*)d_in[0];
    const float* end_pos  = (const float*)d_in[2];
    const float* end_spd  = (const float*)d_in[3];
    const float* Ws  = (const float*)d_in[4];
    const float* bs  = (const float*)d_in[5];
    const float* Wv  = (const float*)d_in[6];
    const float* bv  = (const float*)d_in[7];
    const float* W1  = (const float*)d_in[8];
    const float* b1  = (const float*)d_in[9];
    const float* g1  = (const float*)d_in[10];
    const float* be1 = (const float*)d_in[11];
    const float* W2  = (const float*)d_in[12];
    const float* b2  = (const float*)d_in[13];
    const float* g2  = (const float*)d_in[14];
    const float* be2 = (const float*)d_in[15];
    float* ws = (float*)d_ws;
    float* u1   = ws + 2048;                      // 2,097,152
    float* w1x  = ws + 2099200;                   // 2,097,152
    ushort_t* W2T = (ushort_t*)(ws + 4196352);    // 524,288 bf16
    float* maxv = ws + 4458496;                   // 4,194,304
    float* minv = ws + 8652800;                   // 4,194,304
    float* psum = ws + 12847104;                  // 131,072
    float* psq  = ws + 12978176;                  // 131,072 (contiguous after psum)
    ushort_t* h1 = (ushort_t*)(ws + 13109248);    // CG*1024*512 bf16
    float* out = (float*)d_out;

    // pick largest group-chunk CG whose h1 fits the workspace
    const size_t fixed_f = 13109248ULL;
    int CG = 128;
    while (CG > 4 && (fixed_f + (size_t)CG * 262144ULL) * 4ULL > ws_size) CG >>= 1;
    int nch = 128 / CG;

    hipLaunchKernelGGL(k2_all, dim3(384), dim3(256), 0, stream,
                       h_states, end_pos, end_spd, W1, g1, be1,
                       Ws, bs, Wv, bv, b1, W2, W2T, u1, w1x, psum);
    for (int c = 0; c < nch; c++) {
        const float* u1c = u1 + (size_t)c * CG * 32 * ND1;
        const float* w1c = w1x + (size_t)c * CG * 32 * ND1;
        hipLaunchKernelGGL(k2b_h1, dim3(CG * 256), dim3(256), 0, stream, u1c, w1c, h1);
        hipLaunchKernelGGL(k3_gemm, dim3(CG * 64), dim3(256), 0, stream,
                           h1, W2T, maxv, minv, psum, psq, c * CG);
    }
    hipLaunchKernelGGL(k4_final, dim3(512), dim3(256), 0, stream,
                       maxv, minv, psum, psq, b2, g2, be2, out);
}

// Round 7
// 306.294 us; speedup vs baseline: 1.7918x; 1.0612x over previous
//
#include <hip/hip_runtime.h>
#include <cstdint>

typedef unsigned short ushort_t;
typedef __attribute__((ext_vector_type(8))) __bf16 bf16x8;
typedef __attribute__((ext_vector_type(4))) float f32x4;
typedef __attribute__((ext_vector_type(4))) int i32x4;

#define NG 128
#define NP 32
#define NH 64
#define ND1 512
#define ND2 1024

__device__ inline ushort_t f2bf(float f) {
    uint32_t u = __float_as_uint(f);
    uint32_t r = (u + 0x7FFFu + ((u >> 16) & 1u)) >> 16;
    return (ushort_t)r;
}

#define GLL16(gp, lp) __builtin_amdgcn_global_load_lds( \
    (const __attribute__((address_space(1))) unsigned int*)(gp), \
    (__attribute__((address_space(3))) unsigned int*)(lp), 16, 0, 0)

// K2_all: grid 384.
//  blocks 0..255: zero psum/psq + inline weight-fold + per-(g,ch) BN1 analytics,
//                 emit u1 = (q_j+c_j)*A1+B1 and w1 = q_i*A1  (fp32)
//  blocks 256..383: W2 [512,1024] fp32 -> W2T bf16 [1024][512], stored with
//                 chunk swizzle: 16B chunk c of each 128B window at c^(n&7).
__global__ void k2_all(const float* __restrict__ hstates, const float* __restrict__ pos,
                       const float* __restrict__ spd, const float* __restrict__ W1,
                       const float* __restrict__ g1, const float* __restrict__ be1,
                       const float* __restrict__ Ws, const float* __restrict__ bs,
                       const float* __restrict__ Wv, const float* __restrict__ bv,
                       const float* __restrict__ b1, const float* __restrict__ W2,
                       ushort_t* __restrict__ W2T,
                       float* __restrict__ u1, float* __restrict__ w1,
                       float* __restrict__ psum) {
    __shared__ float hid_s[32][64];
    __shared__ float pos_s[32][2];
    __shared__ float spd_s[32];
    __shared__ ushort_t tile[64][65];
    int b = blockIdx.x, tid = threadIdx.x;
    if (b < 256) {
        int t0 = b * 256 + tid;
        #pragma unroll
        for (int z = 0; z < 4; z++) psum[t0 + z * 65536] = 0.f;
        int g = b >> 1;
        int ch = ((b & 1) << 8) + tid;
        for (int t = tid; t < 2048; t += 256) hid_s[t >> 6][t & 63] = hstates[g * 2048 + t];
        if (tid < 64) pos_s[tid >> 1][tid & 1] = pos[g * 64 + tid];
        if (tid < 32) spd_s[tid] = spd[g * 32 + tid];
        float m0 = 0.f, m1 = 0.f, uu = 0.f, vv = b1[ch];
        for (int e = 0; e < 64; e++) {
            float w1a = W1[e * ND1 + ch];
            float w1c = W1[(128 + e) * ND1 + ch];
            m0 += Ws[e] * w1a;
            m1 += Ws[64 + e] * w1a;
            uu += Wv[e] * w1c;
            vv += bs[e] * w1a + bv[e] * w1c;
        }
        __syncthreads();
        float cj[32], qj[32];
        #pragma unroll
        for (int j = 0; j < 32; j++) {
            qj[j] = pos_s[j][0] * m0 + pos_s[j][1] * m1;
            cj[j] = vv + spd_s[j] * uu;
        }
        for (int h = 0; h < 64; h++) {
            float w = W1[(64 + h) * ND1 + ch];
            #pragma unroll
            for (int j = 0; j < 32; j++) cj[j] += hid_s[j][h] * w;
        }
        float S1 = 0.f, S2 = 0.f, C1 = 0.f, Cq = 0.f, C2 = 0.f;
        #pragma unroll
        for (int j = 0; j < 32; j++) {
            S1 += qj[j]; S2 += qj[j] * qj[j];
            C1 += cj[j]; Cq += cj[j] * qj[j]; C2 += cj[j] * cj[j];
        }
        float mean = C1 * (1.0f / 32.0f);
        float sumsq = 64.f * S2 - 2.f * S1 * S1 + 64.f * Cq - 2.f * S1 * C1 + 32.f * C2;
        float var = sumsq * (1.0f / 1024.0f) - mean * mean;
        float A1 = rsqrtf(var + 1e-5f) * g1[ch];
        float B1 = be1[ch] - mean * A1;
        #pragma unroll
        for (int j = 0; j < 32; j++) {
            u1[(g * 32 + j) * ND1 + ch] = (qj[j] + cj[j]) * A1 + B1;
            w1[(g * 32 + j) * ND1 + ch] = qj[j] * A1;
        }
    } else {
        int tb = b - 256;
        int kb2 = tb & 7, nb = tb >> 3;
        #pragma unroll
        for (int e = 0; e < 16; e++) {
            int lin = tid + e * 256;
            int k = lin >> 6, n = lin & 63;
            tile[k][n] = f2bf(W2[(kb2 * 64 + k) * ND2 + nb * 64 + n]);
        }
        __syncthreads();
        #pragma unroll
        for (int e = 0; e < 16; e++) {
            int lin = tid + e * 256;
            int kl = lin & 63, nl = lin >> 6;
            int n = nb * 64 + nl, k = kb2 * 64 + kl;
            int idx = n * ND1 + ((k >> 6) << 6) + (((((k >> 3) & 7) ^ (n & 7))) << 3) + (k & 7);
            W2T[idx] = tile[kl][nl];
        }
    }
}

// K2b: materialize h1[row][k] = relu(u1[g,j,k] - w1[g,i,k]) as bf16,
// stored with the same chunk swizzle (16B chunk c of each 128B window at c^(row&7)).
__global__ void k2b_h1(const float* __restrict__ u1c, const float* __restrict__ w1c,
                       ushort_t* __restrict__ h1) {
    int t = blockIdx.x * 256 + threadIdx.x;
    int k8 = t & 63;
    int row = t >> 6;
    int gc = row >> 10, rem = row & 1023;
    int i = rem >> 5, j = rem & 31;
    const float4* pu = reinterpret_cast<const float4*>(u1c + (size_t)(gc * 32 + j) * ND1 + k8 * 8);
    const float4* pw = reinterpret_cast<const float4*>(w1c + (size_t)(gc * 32 + i) * ND1 + k8 * 8);
    float4 ua = pu[0], ub = pu[1], wa = pw[0], wb = pw[1];
    uint32_t p0 = (uint32_t)f2bf(fmaxf(ua.x - wa.x, 0.f)) | ((uint32_t)f2bf(fmaxf(ua.y - wa.y, 0.f)) << 16);
    uint32_t p1 = (uint32_t)f2bf(fmaxf(ua.z - wa.z, 0.f)) | ((uint32_t)f2bf(fmaxf(ua.w - wa.w, 0.f)) << 16);
    uint32_t p2 = (uint32_t)f2bf(fmaxf(ub.x - wb.x, 0.f)) | ((uint32_t)f2bf(fmaxf(ub.y - wb.y, 0.f)) << 16);
    uint32_t p3 = (uint32_t)f2bf(fmaxf(ub.z - wb.z, 0.f)) | ((uint32_t)f2bf(fmaxf(ub.w - wb.w, 0.f)) << 16);
    i32x4 v = {(int)p0, (int)p1, (int)p2, (int)p3};
    int kt = k8 >> 3, c = k8 & 7;
    *reinterpret_cast<i32x4*>(h1 + (size_t)row * ND1 + (kt << 6) + (((c ^ (row & 7))) << 3)) = v;
}

// K3: 256x256 8-phase GEMM (m201-style). 8 waves (2Mx4N), BK=64, 128 KiB STATIC
// LDS = 2 K-tile regions (even kt->R0, odd->R1), each [A 32K | B 32K] x 2 halves.
// Per phase: ds_read quadrant subtile, stage 1 half-tile (2xGLL16), raw barrier,
// setprio(1) 16 MFMA setprio(0), barrier. Counted vmcnt(4) at phases 4 & 8.
// Producer-side swizzle (h1/W2T pre-swizzled) keeps ds_reads conflict-free.
#define BARX() do { __builtin_amdgcn_sched_barrier(0); __builtin_amdgcn_s_barrier(); __builtin_amdgcn_sched_barrier(0); } while (0)
#define STG(XG, XL, kt, h) do { \
    const char* _g = (XG) + (size_t)(h) * 131072 + (size_t)(kt) * 128; \
    char* _l = (XL) + (((kt) & 1) << 15) + ((h) << 14) + ldsw; \
    GLL16(_g, _l); \
    GLL16(_g + 65536, _l + 8192); \
} while (0)

__global__ __launch_bounds__(512, 2) void k3_gemm(
        const ushort_t* __restrict__ h1, const ushort_t* __restrict__ W2T,
        float* __restrict__ maxv, float* __restrict__ minv,
        float* __restrict__ psum, float* __restrict__ psq, int g0, int nwg8) {
    __shared__ __align__(16) char lds[131072];
    int b = blockIdx.x;
    int orig = (b & 7) * nwg8 + (b >> 3);
    int mt = orig >> 2, nt = orig & 3;
    int tid = threadIdx.x;
    int w = tid >> 6, l = tid & 63;
    int wm = w >> 2, wn = w & 3;
    int lo = l & 15, lhi = l >> 4;

    // staging addresses
    int srow = w * 8 + (l >> 3);
    int sbyte = (l & 7) * 16;
    const char* Agb = reinterpret_cast<const char*>(h1) + (size_t)(mt * 256 + srow) * 1024 + sbyte;
    const char* Bgb = reinterpret_cast<const char*>(W2T) + (size_t)(nt * 256 + srow) * 1024 + sbyte;
    char* ldsA = lds;
    char* ldsB = lds + 65536;
    int ldsw = w * 1024;

    // ds_read bases (swizzle chunk: (kc*4+lhi)^(lo&7), row&7 == lo&7 everywhere)
    int csw0 = ((lhi) ^ (lo & 7)) << 4;
    int csw1 = ((4 + lhi) ^ (lo & 7)) << 4;
    const char* aRB = ldsA + wm * 16384 + lo * 128;
    const char* bRB = ldsB + (wn >> 1) * 16384 + ((wn & 1) * 64 + lo) * 128;

    f32x4 acc[8][4];
    #pragma unroll
    for (int x = 0; x < 8; x++)
        #pragma unroll
        for (int y = 0; y < 4; y++) acc[x][y] = (f32x4){0.f, 0.f, 0.f, 0.f};

    bf16x8 a0[4][2], a1[4][2], bb0[2][2], bb1[2][2];

    auto rdA = [&](bf16x8 (&ar)[4][2], int slot, int qm) {
        #pragma unroll
        for (int f = 0; f < 4; f++) {
            ar[f][0] = *reinterpret_cast<const bf16x8*>(aRB + slot * 32768 + (qm * 64 + f * 16) * 128 + csw0);
            ar[f][1] = *reinterpret_cast<const bf16x8*>(aRB + slot * 32768 + (qm * 64 + f * 16) * 128 + csw1);
        }
    };
    auto rdB = [&](bf16x8 (&br)[2][2], int slot, int qn) {
        #pragma unroll
        for (int f = 0; f < 2; f++) {
            br[f][0] = *reinterpret_cast<const bf16x8*>(bRB + slot * 32768 + (qn * 2 + f) * 2048 + csw0);
            br[f][1] = *reinterpret_cast<const bf16x8*>(bRB + slot * 32768 + (qn * 2 + f) * 2048 + csw1);
        }
    };
    auto mm = [&](int fr0, int fc0, bf16x8 (&ar)[4][2], bf16x8 (&br)[2][2]) {
        __builtin_amdgcn_s_setprio(1);
        #pragma unroll
        for (int kc = 0; kc < 2; kc++)
            #pragma unroll
            for (int f = 0; f < 4; f++)
                #pragma unroll
                for (int c = 0; c < 2; c++)
                    acc[fr0 + f][fc0 + c] = __builtin_amdgcn_mfma_f32_16x16x32_bf16(
                        ar[f][kc], br[c][kc], acc[fr0 + f][fc0 + c], 0, 0, 0);
        __builtin_amdgcn_s_setprio(0);
    };

    // prologue: stage kt0 (A,B) + kt1 (A,B); wait for kt0
    STG(Agb, ldsA, 0, 0); STG(Agb, ldsA, 0, 1);
    STG(Bgb, ldsB, 0, 0); STG(Bgb, ldsB, 0, 1);
    STG(Agb, ldsA, 1, 0); STG(Agb, ldsA, 1, 1);
    STG(Bgb, ldsB, 1, 0); STG(Bgb, ldsB, 1, 1);
    asm volatile("s_waitcnt vmcnt(8)" ::: "memory");
    BARX();

    for (int J = 0; J < 4; J++) {
        int kB1 = 2 * J + 1;
        // P1: read a0,b0 (R0); stage A(kB1,h0) -> R1.A (J>=1; J0 staged in prologue)
        rdA(a0, 0, 0); rdB(bb0, 0, 0);
        if (J > 0) STG(Agb, ldsA, kB1, 0);
        BARX();
        mm(0, 0, a0, bb0);      // Q00
        BARX();
        // P2: read b1 (R0); stage A(kB1,h1)
        rdB(bb1, 0, 1);
        if (J > 0) STG(Agb, ldsA, kB1, 1);
        BARX();
        mm(0, 2, a0, bb1);      // Q01
        BARX();
        // P3: read a1 (R0); stage B(kB1+1,h0) -> R0.B
        rdA(a1, 0, 1);
        if (J < 3) STG(Bgb, ldsB, kB1 + 1, 0);
        BARX();
        mm(4, 0, a1, bb0);      // Q10
        BARX();
        // P4: stage B(kB1+1,h1); gate: R1 (kt 2J+1) must be fully staged
        if (J < 3) STG(Bgb, ldsB, kB1 + 1, 1);
        BARX();
        mm(4, 2, a1, bb1);      // Q11
        if (J < 3) asm volatile("s_waitcnt vmcnt(4)" ::: "memory");
        else       asm volatile("s_waitcnt vmcnt(0)" ::: "memory");
        BARX();
        // P5: read a0,b0 (R1); stage A(kB1+1,h0) -> R0.A
        rdA(a0, 1, 0); rdB(bb0, 1, 0);
        if (J < 3) STG(Agb, ldsA, kB1 + 1, 0);
        BARX();
        mm(0, 0, a0, bb0);
        BARX();
        // P6: read b1 (R1); stage A(kB1+1,h1)
        rdB(bb1, 1, 1);
        if (J < 3) STG(Agb, ldsA, kB1 + 1, 1);
        BARX();
        mm(0, 2, a0, bb1);
        BARX();
        // P7: read a1 (R1); stage B(kB1+2,h0) -> R1.B
        rdA(a1, 1, 1);
        if (J < 3) STG(Bgb, ldsB, kB1 + 2, 0);
        BARX();
        mm(4, 0, a1, bb0);
        BARX();
        // P8: stage B(kB1+2,h1); gate: R0 (kt 2J+2) must be fully staged
        if (J < 3) STG(Bgb, ldsB, kB1 + 2, 1);
        BARX();
        mm(4, 2, a1, bb1);
        if (J < 3) asm volatile("s_waitcnt vmcnt(4)" ::: "memory");
        BARX();
    }

    // epilogue: rows = wm*128 + x*16 + lhi*4 + r (x=2m+fh); i = qq*8 + wm*4 + m,
    // j = fh*16 + lhi*4 + r; col = nt*256 + wn*64 + fc*16 + lo
    int g = g0 + (mt >> 2);
    int qq = mt & 3;
    #pragma unroll
    for (int fc = 0; fc < 4; fc++) {
        int col = nt * 256 + wn * 64 + fc * 16 + lo;
        float sm = 0.f, sq = 0.f;
        float mx[4], mn[4];
        #pragma unroll
        for (int m = 0; m < 4; m++) {
            float vmx = -1e30f, vmn = 1e30f;
            #pragma unroll
            for (int fh = 0; fh < 2; fh++)
                #pragma unroll
                for (int r = 0; r < 4; r++) {
                    float y = acc[2 * m + fh][fc][r];
                    vmx = fmaxf(vmx, y); vmn = fminf(vmn, y);
                    sm += y; sq += y * y;
                }
            vmx = fmaxf(vmx, __shfl_xor(vmx, 16, 64));
            vmx = fmaxf(vmx, __shfl_xor(vmx, 32, 64));
            vmn = fminf(vmn, __shfl_xor(vmn, 16, 64));
            vmn = fminf(vmn, __shfl_xor(vmn, 32, 64));
            mx[m] = vmx; mn[m] = vmn;
        }
        sm += __shfl_xor(sm, 16, 64); sm += __shfl_xor(sm, 32, 64);
        sq += __shfl_xor(sq, 16, 64); sq += __shfl_xor(sq, 32, 64);
        if (lhi == 0) {
            #pragma unroll
            for (int m = 0; m < 4; m++) {
                int i = qq * 8 + wm * 4 + m;
                size_t idx = (size_t)(g * 32 + i) * ND2 + col;
                maxv[idx] = mx[m]; minv[idx] = mn[m];
            }
            atomicAdd(&psum[g * ND2 + col], sm);
            atomicAdd(&psq[g * ND2 + col], sq);
        }
    }
}

// K4: finalize BN2 (+b2 folded analytically) + relu + max-pool select
__global__ void k4_final(const float* __restrict__ maxv, const float* __restrict__ minv,
                         const float* __restrict__ psum, const float* __restrict__ psq,
                         const float* __restrict__ b2, const float* __restrict__ g2,
                         const float* __restrict__ be2, float* __restrict__ out) {
    int g = blockIdx.x >> 2;
    int col = ((blockIdx.x & 3) << 8) + threadIdx.x;
    float b2v = b2[col];
    float s = psum[g * ND2 + col] * (1.f / 1024.f);
    float q = psq[g * ND2 + col] * (1.f / 1024.f);
    float mean = s + b2v;
    float var = q + 2.f * b2v * s + b2v * b2v - mean * mean;
    float A2 = rsqrtf(var + 1e-5f) * g2[col];
    float B2 = be2[col] - mean * A2;
    for (int i = 0; i < 32; i++) {
        size_t idx = (size_t)(g * 32 + i) * ND2 + col;
        float y = ((A2 >= 0.f) ? maxv[idx] : minv[idx]) + b2v;
        out[idx] = fmaxf(y * A2 + B2, 0.f);
    }
}

extern "C" void kernel_launch(void* const* d_in, const int* in_sizes, int n_in,
                              void* d_out, int out_size, void* d_ws, size_t ws_size,
                              hipStream_t stream) {
    (void)in_sizes; (void)n_in; (void)out_size;
    const float* h_states = (const float*)d_in[0];
    const float* end_pos  = (const float*)d_in[2];
    const float* end_spd  = (const float*)d_in[3];
    const float* Ws  = (const float*)d_in[4];
    const float* bs  = (const float*)d_in[5];
    const float* Wv  = (const float*)d_in[6];
    const float* bv  = (const float*)d_in[7];
    const float* W1  = (const float*)d_in[8];
    const float* b1  = (const float*)d_in[9];
    const float* g1  = (const float*)d_in[10];
    const float* be1 = (const float*)d_in[11];
    const float* W2  = (const float*)d_in[12];
    const float* b2  = (const float*)d_in[13];
    const float* g2  = (const float*)d_in[14];
    const float* be2 = (const float*)d_in[15];
    float* ws = (float*)d_ws;
    float* u1   = ws + 2048;                      // 2,097,152
    float* w1x  = ws + 2099200;                   // 2,097,152
    ushort_t* W2T = (ushort_t*)(ws + 4196352);    // 524,288 bf16
    float* maxv = ws + 4458496;                   // 4,194,304
    float* minv = ws + 8652800;                   // 4,194,304
    float* psum = ws + 12847104;                  // 131,072
    float* psq  = ws + 12978176;                  // 131,072 (contiguous after psum)
    ushort_t* h1 = (ushort_t*)(ws + 13109248);    // CG*1024*512 bf16
    float* out = (float*)d_out;

    const size_t fixed_f = 13109248ULL;
    int CG = 128;
    while (CG > 4 && (fixed_f + (size_t)CG * 262144ULL) * 4ULL > ws_size) CG >>= 1;
    int nch = 128 / CG;

    hipLaunchKernelGGL(k2_all, dim3(384), dim3(256), 0, stream,
                       h_states, end_pos, end_spd, W1, g1, be1,
                       Ws, bs, Wv, bv, b1, W2, W2T, u1, w1x, psum);
    for (int c = 0; c < nch; c++) {
        const float* u1c = u1 + (size_t)c * CG * 32 * ND1;
        const float* w1c = w1x + (size_t)c * CG * 32 * ND1;
        hipLaunchKernelGGL(k2b_h1, dim3(CG * 256), dim3(256), 0, stream, u1c, w1c, h1);
        hipLaunchKernelGGL(k3_gemm, dim3(CG * 16), dim3(512), 0, stream,
                           h1, W2T, maxv, minv, psum, psq, c * CG, CG * 2);
    }
    hipLaunchKernelGGL(k4_final, dim3(512), dim3(256), 0, stream,
                       maxv, minv, psum, psq, b2, g2, be2, out);
}